// Round 1
// baseline (822.005 us; speedup 1.0000x reference)
//
#include <hip/hip_runtime.h>
#include <math.h>

#define DIM   128
#define BATCH 4096
#define NSUB  20
#define NNEG  5

// stable log_sigmoid(x) = min(x,0) - log1p(exp(-|x|))
__device__ __forceinline__ float log_sigmoid(float x) {
    return fminf(x, 0.0f) - log1pf(expf(-fabsf(x)));
}

__global__ __launch_bounds__(64) void fasttext_loss_kernel(
    const int* __restrict__ u_pos,
    const int* __restrict__ v_pos,
    const int* __restrict__ v_neg,
    const float* __restrict__ u_weight,
    const float* __restrict__ v_weight,
    float* __restrict__ out)
{
    const int b    = blockIdx.x;
    const int lane = threadIdx.x;          // 0..63, lane owns dims [2*lane, 2*lane+1]

    float2 eu = make_float2(0.f, 0.f);
    float2 ev = make_float2(0.f, 0.f);

    #pragma unroll
    for (int s = 0; s < NSUB; ++s) {
        const int iu = u_pos[b * NSUB + s];   // wave-uniform -> s_load
        const int iv = v_pos[b * NSUB + s];
        const float2 tv = *(const float2*)(v_weight + (size_t)iv * DIM + lane * 2);
        ev.x += tv.x; ev.y += tv.y;
        if (iu != 0) {                        // padding_idx = 0 on u table
            const float2 tu = *(const float2*)(u_weight + (size_t)iu * DIM + lane * 2);
            eu.x += tu.x; eu.y += tu.y;
        }
    }
    const float inv = 1.0f / NSUB;
    eu.x *= inv; eu.y *= inv;
    ev.x *= inv; ev.y *= inv;

    // positive score: dot(embed_u, embed_v) across 128 dims
    float score = eu.x * ev.x + eu.y * ev.y;
    #pragma unroll
    for (int o = 32; o >= 1; o >>= 1) score += __shfl_xor(score, o, 64);

    float loss = log_sigmoid(score);

    // negatives: 5 accumulators, s-outer loop for load ILP
    float2 nv[NNEG];
    #pragma unroll
    for (int n = 0; n < NNEG; ++n) nv[n] = make_float2(0.f, 0.f);

    #pragma unroll
    for (int s = 0; s < NSUB; ++s) {
        #pragma unroll
        for (int n = 0; n < NNEG; ++n) {
            const int idx = v_neg[(b * NSUB + s) * NNEG + n];  // wave-uniform
            const float2 t = *(const float2*)(v_weight + (size_t)idx * DIM + lane * 2);
            nv[n].x += t.x; nv[n].y += t.y;
        }
    }

    #pragma unroll
    for (int n = 0; n < NNEG; ++n) {
        float ns = (nv[n].x * eu.x + nv[n].y * eu.y) * inv;
        #pragma unroll
        for (int o = 32; o >= 1; o >>= 1) ns += __shfl_xor(ns, o, 64);
        loss += log_sigmoid(-ns);
    }

    if (lane == 0) {
        atomicAdd(out, -loss * (1.0f / (float)BATCH));
    }
}

extern "C" void kernel_launch(void* const* d_in, const int* in_sizes, int n_in,
                              void* d_out, int out_size, void* d_ws, size_t ws_size,
                              hipStream_t stream) {
    const int*   u_pos    = (const int*)d_in[0];
    const int*   v_pos    = (const int*)d_in[1];
    const int*   v_neg    = (const int*)d_in[2];
    // d_in[3] = batch_size scalar (fixed 4096, hardcoded)
    const float* u_weight = (const float*)d_in[4];
    const float* v_weight = (const float*)d_in[5];
    float*       out      = (float*)d_out;

    hipMemsetAsync(out, 0, sizeof(float), stream);
    fasttext_loss_kernel<<<BATCH, 64, 0, stream>>>(u_pos, v_pos, v_neg,
                                                   u_weight, v_weight, out);
}